// Round 17
// baseline (224.706 us; speedup 1.0000x reference)
//
#include <hip/hip_runtime.h>
#include <hip/hip_fp16.h>

// b=2, c=64, 48x48 -> n=2304, heads=4, hd=16. n = 9*256 = 144*16.
// QK^T: q,k as f16 split pairs [v16|res16]; 2 MFMAs give fp32-ish logits.
// k_ent: single-pass MFMA QK^T (entropy shift-invariant, r16-verified) +
// row-major f16 logit cache store. k_attn: cache rows -> registers,
// float-domain ballot top-k, masked exp (NO max - softmax shift-invariant,
// same identity r16 validated), one LDS write of p, MFMA PV, FUSED output
// projection via atomicAdd (k_proj launch + oh round-trip eliminated).
// k_dw: 432 blocks (8ch each; 216 was <1 block/CU latency-bound).

#define NEG_INF (-__builtin_huge_valf())

typedef _Float16 half8_t __attribute__((ext_vector_type(8)));
typedef float floatx4 __attribute__((ext_vector_type(4)));

__device__ __forceinline__ float key16_to_float(unsigned k) {
  unsigned short u = (k & 0x8000u) ? (unsigned short)(k & 0x7FFFu)
                                   : (unsigned short)((~k) & 0xFFFFu);
  return __half2float(__ushort_as_half(u));
}

__device__ __forceinline__ void unpack8(uint4 v, float* o) {
  float2 f0 = __half22float2(*(__half2*)&v.x);
  float2 f1 = __half22float2(*(__half2*)&v.y);
  float2 f2 = __half22float2(*(__half2*)&v.z);
  float2 f3 = __half22float2(*(__half2*)&v.w);
  o[0] = f0.x; o[1] = f0.y; o[2] = f1.x; o[3] = f1.y;
  o[4] = f2.x; o[5] = f2.y; o[6] = f3.x; o[7] = f3.y;
}

// K1: 1x1 conv, 4 output channels per block. grid = 2*48*9 = 864;
// also zeroes ent[] (replaces memset dispatch).
__global__ __launch_bounds__(256) void k_qkv(const float* __restrict__ x,
                                             const float* __restrict__ W,
                                             const float* __restrict__ bias,
                                             float* __restrict__ out,
                                             float* __restrict__ ent) {
  if (blockIdx.x == 0 && threadIdx.x < 8) ent[threadIdx.x] = 0.f;
  int blk = blockIdx.x;
  int chunk = blk % 9;
  int og = (blk / 9) % 48;
  int b = blk / (9 * 48);
  int o0 = og * 4;
  int pos = chunk * 256 + threadIdx.x;
  const float* xb = x + b * 64 * 2304 + pos;
  const float* w0 = W + (o0 + 0) * 64;
  const float* w1 = W + (o0 + 1) * 64;
  const float* w2 = W + (o0 + 2) * 64;
  const float* w3 = W + (o0 + 3) * 64;
  float a0 = bias[o0 + 0], a1 = bias[o0 + 1];
  float a2 = bias[o0 + 2], a3 = bias[o0 + 3];
#pragma unroll
  for (int c = 0; c < 64; c++) {
    float xv = xb[c * 2304];
    a0 = fmaf(w0[c], xv, a0);
    a1 = fmaf(w1[c], xv, a1);
    a2 = fmaf(w2[c], xv, a2);
    a3 = fmaf(w3[c], xv, a3);
  }
  out[(b * 192 + o0 + 0) * 2304 + pos] = a0;
  out[(b * 192 + o0 + 1) * 2304 + pos] = a1;
  out[(b * 192 + o0 + 2) * 2304 + pos] = a2;
  out[(b * 192 + o0 + 3) * 2304 + pos] = a3;
}

// K2: 3x3 depthwise conv, 8 channels per block with LDS staging; q/k
// packed per-row-half stores (2x 16B contiguous). grid = 432.
__global__ __launch_bounds__(256) void k_dw(const float* __restrict__ qkv,
                                            const float* __restrict__ Wpos,
                                            const float* __restrict__ bpos,
                                            _Float16* __restrict__ q2,
                                            _Float16* __restrict__ k2,
                                            _Float16* __restrict__ vt) {
  __shared__ float smem[8][384];  // 8 ch x 8 rows x 48 = 12.3 KB
  int blk = blockIdx.x;
  int chunk = blk % 9;
  int half = (blk / 9) % 2;
  int sel = (blk / 18) % 3;
  int head = (blk / 54) % 4;
  int b = blk / 216;
  int chbase = sel * 64 + head * 16 + half * 8;
  int bh = b * 4 + head;
  int tid = threadIdx.x;
  int p0 = chunk * 256;
  int baserow = p0 / 48;
  int rA = min(max(baserow - 1, 0), 40);  // 8-row window within [0,47]

  const float* src = qkv + (size_t)(b * 192 + chbase) * 2304;
#pragma unroll
  for (int l = 0; l < 12; l++) {
    int idx = tid + l * 256;
    int ch = idx / 384;
    int off = idx - ch * 384;
    int rr = off / 48;
    int cc = off - rr * 48;
    smem[ch][off] = src[(size_t)ch * 2304 + (rA + rr) * 48 + cc];
  }
  __syncthreads();

  int pos = p0 + tid;
  int yy = pos / 48, xx = pos - yy * 48;
  int ry = yy - rA;
  float accv[8];
#pragma unroll
  for (int d = 0; d < 8; d++) {
    const float* w = Wpos + (chbase + d) * 9;
    float a = bpos[chbase + d];
#pragma unroll
    for (int dy = -1; dy <= 1; dy++) {
      int y2 = yy + dy;
      if ((unsigned)y2 < 48u) {
#pragma unroll
        for (int dx = -1; dx <= 1; dx++) {
          int x2 = xx + dx;
          if ((unsigned)x2 < 48u)
            a = fmaf(w[(dy + 1) * 3 + (dx + 1)], smem[d][(ry + dy) * 48 + x2],
                     a);
        }
      }
    }
    accv[d] = a;
  }

  if (sel == 2) {
#pragma unroll
    for (int d = 0; d < 8; d++)
      vt[((size_t)bh * 16 + half * 8 + d) * 2304 + pos] = (_Float16)accv[d];
  } else {
    _Float16 h1[8], h2[8];
#pragma unroll
    for (int d = 0; d < 8; d++) {
      float a = (sel == 0) ? accv[d] * 0.25f : accv[d];
      h1[d] = (_Float16)a;
      h2[d] = (_Float16)(a - (float)h1[d]);
    }
    _Float16* dst = ((sel == 0) ? q2 : k2) + ((size_t)bh * 2304 + pos) * 32;
    *(uint4*)(dst + half * 8) = *(uint4*)&h1[0];
    *(uint4*)(dst + 16 + half * 8) = *(uint4*)&h2[0];
  }
}

// K3: SINGLE-PASS MFMA QK^T: entropy sums (shift-invariant, no max) +
// (STORE) transposed f16 cache store. grid = 8*144, 256 thr.
template <bool STORE>
__global__ __launch_bounds__(256) void k_ent_t(const _Float16* __restrict__ q2,
                                               const _Float16* __restrict__ k2,
                                               float* __restrict__ ent,
                                               _Float16* __restrict__ lgH) {
  __shared__ __align__(16) _Float16 tBuf[4][16][72];
  __shared__ float sWv[4][16], uWv[4][16];

  int blk = blockIdx.x;
  int rowtile = blk % 144;
  int bh = blk / 144;
  int row0 = rowtile * 16;
  int tid = threadIdx.x, lane = tid & 63, wave = tid >> 6;
  int m16 = lane & 15, quad = lane >> 4;

  const half8_t* q2v =
      (const half8_t*)(q2 + ((size_t)bh * 2304 + row0 + m16) * 32);
  half8_t A1 = q2v[quad];
  half8_t zh = {};
  half8_t A2 = (lane < 32) ? A1 : zh;
  const half8_t* kbase = (const half8_t*)(k2 + (size_t)bh * 2304 * 32);

  // s0 = sum e^a, u0 = sum a e^a  (entropy = log s0 - u0/s0; shift-inv.)
  float s[4] = {0.f, 0.f, 0.f, 0.f}, u[4] = {0.f, 0.f, 0.f, 0.f};
  for (int g = 0; g < 9; g++) {
#pragma unroll
    for (int tt = 0; tt < 4; tt++) {
      int t = g * 4 + tt;
      int col = wave * 576 + t * 16 + m16;
      const half8_t* kk = kbase + (size_t)col * 4;
      half8_t b1 = kk[quad & 1];
      half8_t b2 = kk[2 + (quad & 1)];
      floatx4 acc = {};
      acc = __builtin_amdgcn_mfma_f32_16x16x32_f16(A2, b2, acc, 0, 0, 0);
      acc = __builtin_amdgcn_mfma_f32_16x16x32_f16(A1, b1, acc, 0, 0, 0);
#pragma unroll
      for (int i = 0; i < 4; i++) {
        if (STORE) tBuf[wave][quad * 4 + i][tt * 16 + m16] = (_Float16)acc[i];
        float e = __expf(acc[i]);
        s[i] += e;
        u[i] = fmaf(acc[i], e, u[i]);
      }
    }
    if (STORE) {
      __syncthreads();
      int rb = lane >> 3, seg = lane & 7;
#pragma unroll
      for (int it = 0; it < 2; it++) {
        int rr = it * 8 + rb;
        uint4 vv = *(const uint4*)&tBuf[wave][rr][seg * 8];
        *(uint4*)(lgH + ((size_t)bh * 2304 + row0 + rr) * 2304 + wave * 576 +
                  g * 64 + seg * 8) = vv;
      }
      __syncthreads();
    }
  }
#pragma unroll
  for (int off = 1; off < 16; off <<= 1) {
#pragma unroll
    for (int i = 0; i < 4; i++) {
      s[i] += __shfl_xor(s[i], off);
      u[i] += __shfl_xor(u[i], off);
    }
  }
  if (m16 == 0) {
#pragma unroll
    for (int i = 0; i < 4; i++) {
      sWv[wave][quad * 4 + i] = s[i];
      uWv[wave][quad * 4 + i] = u[i];
    }
  }
  __syncthreads();
  if (tid < 16) {
    float S = sWv[0][tid] + sWv[1][tid] + sWv[2][tid] + sWv[3][tid];
    float U = uWv[0][tid] + uWv[1][tid] + uWv[2][tid] + uWv[3][tid];
    float er = __logf(S) - U / S;
    er += __shfl_xor(er, 1);
    er += __shfl_xor(er, 2);
    er += __shfl_xor(er, 4);
    er += __shfl_xor(er, 8);
    if (tid == 0) atomicAdd(&ent[bh], er);
  }
}

// K5: gate MLP + per-row top-k + masked softmax (no max; shift-invariant)
// + MFMA PV + FUSED output projection (atomicAdd into out; head 0 adds
// bias). XCD remap: a%8 == rowtile%8 == writer k_ent block %8.
template <bool CACHED>
__global__ __launch_bounds__(256, 7) void k_attn_t(
    const _Float16* __restrict__ q2, const _Float16* __restrict__ k2,
    const _Float16* __restrict__ vt, const _Float16* __restrict__ lgH,
    const float* __restrict__ ent, const float* __restrict__ Wg1,
    const float* __restrict__ bg1, const float* __restrict__ Wg2,
    const float* __restrict__ bg2, const float* __restrict__ Wp,
    const float* __restrict__ bp, float* __restrict__ out) {
  __shared__ __align__(16) _Float16 pbuf[4][2320];
  __shared__ float sS[4];
  __shared__ __align__(16) float redSh[4][64];
  __shared__ float oSh[4][16];

  // XCD-affinity decode: a%8 == rowtile%8 == (bh*144+rowtile)%8 (writer).
  int a = blockIdx.x;
  int v8 = a & 7;
  int idx = a >> 3;
  int q = idx & 3;
  int pi = idx >> 2;              // 0..143
  int bh = pi / 18;
  int rowtile = v8 + (pi % 18) * 8;
  int rowblk = rowtile * 4 + q;
  int row0 = rowblk * 4;
  int tid = threadIdx.x, lane = tid & 63, wave = tid >> 6;

  // ---- gate MLP (uniform) ----
  float eAvg = ent[bh] * (1.f / 2304.f);
  float gacc = bg2[0];
#pragma unroll
  for (int i = 0; i < 16; i++) {
    float h = fmaxf(fmaf(eAvg, Wg1[i], bg1[i]), 0.f);
    gacc = fmaf(h, Wg2[i], gacc);
  }
  float ratio = 0.9f / (1.f + __expf(-gacc)) + 0.1f;
  int kp = (int)ceilf(ratio * 2304.f);
  unsigned keep = (unsigned)min(max(kp, 1), 2304);

  // ---- phase A: own row -> 36 register floats (no max needed) ----
  float v[36];
  if (CACHED) {
    const _Float16* src = lgH + ((size_t)bh * 2304 + row0 + wave) * 2304;
    const uint4* s4 = (const uint4*)src;
#pragma unroll
    for (int it = 0; it < 4; it++) {
      uint4 r = s4[lane + it * 64];
      unpack8(r, &v[it * 8]);
    }
    {
      uint2 r2 = *(const uint2*)(src + 2048 + lane * 4);
      float2 f0 = __half22float2(*(__half2*)&r2.x);
      float2 f1 = __half22float2(*(__half2*)&r2.y);
      v[32] = f0.x; v[33] = f0.y; v[34] = f1.x; v[35] = f1.y;
    }
  } else {
    int m16 = lane & 15, quad = lane >> 4;
    const half8_t* q2v =
        (const half8_t*)(q2 + ((size_t)bh * 2304 + row0 + (m16 & 3)) * 32);
    half8_t A1 = q2v[quad];
    half8_t zh = {};
    half8_t A2 = (lane < 32) ? A1 : zh;
    const half8_t* kbase = (const half8_t*)(k2 + (size_t)bh * 2304 * 32);
#pragma unroll 4
    for (int t = 0; t < 36; t++) {
      int ct = wave * 36 + t;
      int col = ct * 16 + m16;
      const half8_t* kk = kbase + (size_t)col * 4;
      half8_t b1 = kk[quad & 1];
      half8_t b2 = kk[2 + (quad & 1)];
      floatx4 acc = {};
      acc = __builtin_amdgcn_mfma_f32_16x16x32_f16(A2, b2, acc, 0, 0, 0);
      acc = __builtin_amdgcn_mfma_f32_16x16x32_f16(A1, b1, acc, 0, 0, 0);
      if (lane < 16) {
#pragma unroll
        for (int i = 0; i < 4; i++) pbuf[i][ct * 16 + lane] = (_Float16)acc[i];
      }
    }
    __syncthreads();
    const _Float16* src = pbuf[wave];
    const uint4* s4 = (const uint4*)src;
#pragma unroll
    for (int it = 0; it < 4; it++) unpack8(s4[lane + it * 64], &v[it * 8]);
    uint2 r2 = *(const uint2*)(src + 2048 + lane * 4);
    float2 f0 = __half22float2(*(__half2*)&r2.x);
    float2 f1 = __half22float2(*(__half2*)&r2.y);
    v[32] = f0.x; v[33] = f0.y; v[34] = f1.x; v[35] = f1.y;
  }

  // ---- phase B: exact k-th largest, float-domain ballot bit-search ----
  float th;
  {
    unsigned T = 0u;
    for (int bit = 15; bit >= 0; --bit) {
      unsigned cand = T | (1u << bit);
      float cf = key16_to_float(cand);
      unsigned cnt = 0u;
#pragma unroll
      for (int i = 0; i < 36; i++)
        cnt += (unsigned)__popcll(__ballot(v[i] >= cf));
      if (cnt >= keep) {
        T = cand;  // uniform
        if (cnt == keep) break;
      }
    }
    th = key16_to_float(T);
  }

  // ---- phase C1: masked exp (raw; softmax shift-invariant); p -> LDS ----
  {
    float sp = 0.f;
    uint4* prow4 = (uint4*)pbuf[wave];
#pragma unroll
    for (int it = 0; it < 4; it++) {
      float p[8];
#pragma unroll
      for (int e = 0; e < 8; e++) {
        float av = v[it * 8 + e];
        p[e] = (av >= th) ? __expf(av) : 0.f;
        sp += p[e];
      }
      uint4 o;
      __half2 h0 = __floats2half2_rn(p[0], p[1]); o.x = *(unsigned*)&h0;
      __half2 h1 = __floats2half2_rn(p[2], p[3]); o.y = *(unsigned*)&h1;
      __half2 h2 = __floats2half2_rn(p[4], p[5]); o.z = *(unsigned*)&h2;
      __half2 h3 = __floats2half2_rn(p[6], p[7]); o.w = *(unsigned*)&h3;
      prow4[lane + it * 64] = o;
    }
    {
      float p0 = (v[32] >= th) ? __expf(v[32]) : 0.f;
      float p1 = (v[33] >= th) ? __expf(v[33]) : 0.f;
      float p2 = (v[34] >= th) ? __expf(v[34]) : 0.f;
      float p3 = (v[35] >= th) ? __expf(v[35]) : 0.f;
      sp += (p0 + p1) + (p2 + p3);
      uint2 o;
      __half2 h0 = __floats2half2_rn(p0, p1); o.x = *(unsigned*)&h0;
      __half2 h1 = __floats2half2_rn(p2, p3); o.y = *(unsigned*)&h1;
      *(uint2*)(pbuf[wave] + 2048 + lane * 4) = o;
    }
#pragma unroll
    for (int off = 1; off < 64; off <<= 1) sp += __shfl_xor(sp, off);
    if (lane == 0) sS[wave] = sp;
  }
  __syncthreads();  // all rows' p visible; sS visible

  // ---- phase C2: PV via MFMA; wave = j-quarter ----
  {
    int m16 = lane & 15, quad = lane >> 4;
    const _Float16* vrow = vt + ((size_t)bh * 16 + m16) * 2304;
    const _Float16* prow = pbuf[m16 & 3];
    int jb0 = wave * 576 + quad * 8;
    floatx4 acc = {};
#pragma unroll 6
    for (int t = 0; t < 18; t++) {
      int jb = jb0 + t * 32;
      half8_t a2 = *(const half8_t*)&prow[jb];
      half8_t b2 = *(const half8_t*)&vrow[jb];
      acc = __builtin_amdgcn_mfma_f32_16x16x32_f16(a2, b2, acc, 0, 0, 0);
    }
    if (lane < 16) {  // quad 0: D rows 0-3 = our rows, col = m16 = d
      *(floatx4*)&redSh[wave][m16 * 4] = acc;
    }
  }
  __syncthreads();
  if (tid < 64) {
    int r = tid & 3, d = tid >> 2;
    float s2 = redSh[0][d * 4 + r] + redSh[1][d * 4 + r] +
               redSh[2][d * 4 + r] + redSh[3][d * 4 + r];
    oSh[r][d] = s2 / sS[r];
  }
  __syncthreads();

  // ---- fused projection: thread (r=wave, co=lane) -> atomicAdd out ----
  {
    int r = wave;
    int co = lane;
    int head = bh & 3, b = bh >> 2;
    const float* wr = Wp + co * 64 + head * 16;
    float val = 0.f;
#pragma unroll
    for (int d = 0; d < 16; d++) val = fmaf(wr[d], oSh[r][d], val);
    if (head == 0) val += bp[co];
    atomicAdd(&out[((size_t)(b * 64 + co)) * 2304 + row0 + r], val);
  }
}

extern "C" void kernel_launch(void* const* d_in, const int* in_sizes, int n_in,
                              void* d_out, int out_size, void* d_ws,
                              size_t ws_size, hipStream_t stream) {
  const float* x    = (const float*)d_in[0];
  const float* Wqkv = (const float*)d_in[1];
  const float* bqkv = (const float*)d_in[2];
  const float* Wpos = (const float*)d_in[3];
  const float* bpos = (const float*)d_in[4];
  const float* Wg1  = (const float*)d_in[5];
  const float* bg1  = (const float*)d_in[6];
  const float* Wg2  = (const float*)d_in[7];
  const float* bg2  = (const float*)d_in[8];
  const float* Wpr  = (const float*)d_in[9];
  const float* bpr  = (const float*)d_in[10];
  float* out = (float*)d_out;

  // row-major f16 logit cache: 8 bh * 2304 * 2304 * 2 B = 84,934,656 B
  const size_t lgBytes = (size_t)8 * 2304 * 2304 * 2;
  const size_t baseBytes = (size_t)(884736 + 8) * 4 +
                           (size_t)(2 * 589824 + 294912) * 2;
  bool cached = ws_size >= lgBytes + baseBytes;

  char* base = (char*)d_ws;
  _Float16* lgH = nullptr;
  if (cached) {
    lgH = (_Float16*)base;
    base += lgBytes;
  }
  float* qkv_raw = (float*)base;        // 884736 floats
  float* ent = qkv_raw + 884736;        // 8 floats
  _Float16* q2 = (_Float16*)(ent + 8);  // 589824 halves
  _Float16* k2 = q2 + 589824;           // 589824 halves
  _Float16* vt = k2 + 589824;           // 294912 halves (V^T f16 [bh][d][j])

  (void)hipMemsetAsync(out, 0, (size_t)out_size * sizeof(float), stream);
  hipLaunchKernelGGL(k_qkv, dim3(2 * 48 * 9), dim3(256), 0, stream,
                     x, Wqkv, bqkv, qkv_raw, ent);
  hipLaunchKernelGGL(k_dw, dim3(432), dim3(256), 0, stream,
                     qkv_raw, Wpos, bpos, q2, k2, vt);
  if (cached) {
    hipLaunchKernelGGL((k_ent_t<true>), dim3(8 * 144), dim3(256), 0, stream,
                       q2, k2, ent, lgH);
    hipLaunchKernelGGL((k_attn_t<true>), dim3(8 * 576), dim3(256), 0, stream,
                       q2, k2, vt, lgH, ent, Wg1, bg1, Wg2, bg2, Wpr, bpr,
                       out);
  } else {
    hipLaunchKernelGGL((k_ent_t<false>), dim3(8 * 144), dim3(256), 0, stream,
                       q2, k2, ent, lgH);
    hipLaunchKernelGGL((k_attn_t<false>), dim3(8 * 576), dim3(256), 0, stream,
                       q2, k2, vt, lgH, ent, Wg1, bg1, Wg2, bg2, Wpr, bpr,
                       out);
  }
}

// Round 18
// 198.563 us; speedup vs baseline: 1.1317x; 1.1317x over previous
//
#include <hip/hip_runtime.h>
#include <hip/hip_fp16.h>

// b=2, c=64, 48x48 -> n=2304, heads=4, hd=16. n = 9*256 = 144*16.
// QK^T: q,k as f16 split pairs [v16|res16]; 2 MFMAs give fp32-ish logits.
// k_ent: single-pass MFMA QK^T (entropy shift-invariant, r16-verified) +
// row-major f16 logit cache store. k_attn: cache rows -> registers,
// float-domain ballot top-k, masked exp with NO max (shift-invariant,
// r17-validated), one LDS write of p, MFMA PV -> oh. SEPARATE k_proj
// (r17's fused atomicAdd projection measured 60->94us: 9216B-stride
// 64-lane atomic scatter, 37MB HBM writes - do not revisit).
// k_dw: 432 blocks (8ch each; r17-kept).

#define NEG_INF (-__builtin_huge_valf())

typedef _Float16 half8_t __attribute__((ext_vector_type(8)));
typedef float floatx4 __attribute__((ext_vector_type(4)));

__device__ __forceinline__ float key16_to_float(unsigned k) {
  unsigned short u = (k & 0x8000u) ? (unsigned short)(k & 0x7FFFu)
                                   : (unsigned short)((~k) & 0xFFFFu);
  return __half2float(__ushort_as_half(u));
}

__device__ __forceinline__ void unpack8(uint4 v, float* o) {
  float2 f0 = __half22float2(*(__half2*)&v.x);
  float2 f1 = __half22float2(*(__half2*)&v.y);
  float2 f2 = __half22float2(*(__half2*)&v.z);
  float2 f3 = __half22float2(*(__half2*)&v.w);
  o[0] = f0.x; o[1] = f0.y; o[2] = f1.x; o[3] = f1.y;
  o[4] = f2.x; o[5] = f2.y; o[6] = f3.x; o[7] = f3.y;
}

// K1: 1x1 conv, 4 output channels per block. grid = 2*48*9 = 864;
// also zeroes ent[] (replaces memset dispatch).
__global__ __launch_bounds__(256) void k_qkv(const float* __restrict__ x,
                                             const float* __restrict__ W,
                                             const float* __restrict__ bias,
                                             float* __restrict__ out,
                                             float* __restrict__ ent) {
  if (blockIdx.x == 0 && threadIdx.x < 8) ent[threadIdx.x] = 0.f;
  int blk = blockIdx.x;
  int chunk = blk % 9;
  int og = (blk / 9) % 48;
  int b = blk / (9 * 48);
  int o0 = og * 4;
  int pos = chunk * 256 + threadIdx.x;
  const float* xb = x + b * 64 * 2304 + pos;
  const float* w0 = W + (o0 + 0) * 64;
  const float* w1 = W + (o0 + 1) * 64;
  const float* w2 = W + (o0 + 2) * 64;
  const float* w3 = W + (o0 + 3) * 64;
  float a0 = bias[o0 + 0], a1 = bias[o0 + 1];
  float a2 = bias[o0 + 2], a3 = bias[o0 + 3];
#pragma unroll
  for (int c = 0; c < 64; c++) {
    float xv = xb[c * 2304];
    a0 = fmaf(w0[c], xv, a0);
    a1 = fmaf(w1[c], xv, a1);
    a2 = fmaf(w2[c], xv, a2);
    a3 = fmaf(w3[c], xv, a3);
  }
  out[(b * 192 + o0 + 0) * 2304 + pos] = a0;
  out[(b * 192 + o0 + 1) * 2304 + pos] = a1;
  out[(b * 192 + o0 + 2) * 2304 + pos] = a2;
  out[(b * 192 + o0 + 3) * 2304 + pos] = a3;
}

// K2: 3x3 depthwise conv, 8 channels per block with LDS staging; q/k
// packed per-row-half stores (2x 16B contiguous). grid = 432.
__global__ __launch_bounds__(256) void k_dw(const float* __restrict__ qkv,
                                            const float* __restrict__ Wpos,
                                            const float* __restrict__ bpos,
                                            _Float16* __restrict__ q2,
                                            _Float16* __restrict__ k2,
                                            _Float16* __restrict__ vt) {
  __shared__ float smem[8][384];  // 8 ch x 8 rows x 48 = 12.3 KB
  int blk = blockIdx.x;
  int chunk = blk % 9;
  int half = (blk / 9) % 2;
  int sel = (blk / 18) % 3;
  int head = (blk / 54) % 4;
  int b = blk / 216;
  int chbase = sel * 64 + head * 16 + half * 8;
  int bh = b * 4 + head;
  int tid = threadIdx.x;
  int p0 = chunk * 256;
  int baserow = p0 / 48;
  int rA = min(max(baserow - 1, 0), 40);  // 8-row window within [0,47]

  const float* src = qkv + (size_t)(b * 192 + chbase) * 2304;
#pragma unroll
  for (int l = 0; l < 12; l++) {
    int idx = tid + l * 256;
    int ch = idx / 384;
    int off = idx - ch * 384;
    int rr = off / 48;
    int cc = off - rr * 48;
    smem[ch][off] = src[(size_t)ch * 2304 + (rA + rr) * 48 + cc];
  }
  __syncthreads();

  int pos = p0 + tid;
  int yy = pos / 48, xx = pos - yy * 48;
  int ry = yy - rA;
  float accv[8];
#pragma unroll
  for (int d = 0; d < 8; d++) {
    const float* w = Wpos + (chbase + d) * 9;
    float a = bpos[chbase + d];
#pragma unroll
    for (int dy = -1; dy <= 1; dy++) {
      int y2 = yy + dy;
      if ((unsigned)y2 < 48u) {
#pragma unroll
        for (int dx = -1; dx <= 1; dx++) {
          int x2 = xx + dx;
          if ((unsigned)x2 < 48u)
            a = fmaf(w[(dy + 1) * 3 + (dx + 1)], smem[d][(ry + dy) * 48 + x2],
                     a);
        }
      }
    }
    accv[d] = a;
  }

  if (sel == 2) {
#pragma unroll
    for (int d = 0; d < 8; d++)
      vt[((size_t)bh * 16 + half * 8 + d) * 2304 + pos] = (_Float16)accv[d];
  } else {
    _Float16 h1[8], h2[8];
#pragma unroll
    for (int d = 0; d < 8; d++) {
      float a = (sel == 0) ? accv[d] * 0.25f : accv[d];
      h1[d] = (_Float16)a;
      h2[d] = (_Float16)(a - (float)h1[d]);
    }
    _Float16* dst = ((sel == 0) ? q2 : k2) + ((size_t)bh * 2304 + pos) * 32;
    *(uint4*)(dst + half * 8) = *(uint4*)&h1[0];
    *(uint4*)(dst + 16 + half * 8) = *(uint4*)&h2[0];
  }
}

// K3: SINGLE-PASS MFMA QK^T: entropy sums (shift-invariant, no max) +
// (STORE) transposed f16 cache store. grid = 8*144, 256 thr.
template <bool STORE>
__global__ __launch_bounds__(256) void k_ent_t(const _Float16* __restrict__ q2,
                                               const _Float16* __restrict__ k2,
                                               float* __restrict__ ent,
                                               _Float16* __restrict__ lgH) {
  __shared__ __align__(16) _Float16 tBuf[4][16][72];
  __shared__ float sWv[4][16], uWv[4][16];

  int blk = blockIdx.x;
  int rowtile = blk % 144;
  int bh = blk / 144;
  int row0 = rowtile * 16;
  int tid = threadIdx.x, lane = tid & 63, wave = tid >> 6;
  int m16 = lane & 15, quad = lane >> 4;

  const half8_t* q2v =
      (const half8_t*)(q2 + ((size_t)bh * 2304 + row0 + m16) * 32);
  half8_t A1 = q2v[quad];
  half8_t zh = {};
  half8_t A2 = (lane < 32) ? A1 : zh;
  const half8_t* kbase = (const half8_t*)(k2 + (size_t)bh * 2304 * 32);

  // s0 = sum e^a, u0 = sum a e^a  (entropy = log s0 - u0/s0; shift-inv.)
  float s[4] = {0.f, 0.f, 0.f, 0.f}, u[4] = {0.f, 0.f, 0.f, 0.f};
  for (int g = 0; g < 9; g++) {
#pragma unroll
    for (int tt = 0; tt < 4; tt++) {
      int t = g * 4 + tt;
      int col = wave * 576 + t * 16 + m16;
      const half8_t* kk = kbase + (size_t)col * 4;
      half8_t b1 = kk[quad & 1];
      half8_t b2 = kk[2 + (quad & 1)];
      floatx4 acc = {};
      acc = __builtin_amdgcn_mfma_f32_16x16x32_f16(A2, b2, acc, 0, 0, 0);
      acc = __builtin_amdgcn_mfma_f32_16x16x32_f16(A1, b1, acc, 0, 0, 0);
#pragma unroll
      for (int i = 0; i < 4; i++) {
        if (STORE) tBuf[wave][quad * 4 + i][tt * 16 + m16] = (_Float16)acc[i];
        float e = __expf(acc[i]);
        s[i] += e;
        u[i] = fmaf(acc[i], e, u[i]);
      }
    }
    if (STORE) {
      __syncthreads();
      int rb = lane >> 3, seg = lane & 7;
#pragma unroll
      for (int it = 0; it < 2; it++) {
        int rr = it * 8 + rb;
        uint4 vv = *(const uint4*)&tBuf[wave][rr][seg * 8];
        *(uint4*)(lgH + ((size_t)bh * 2304 + row0 + rr) * 2304 + wave * 576 +
                  g * 64 + seg * 8) = vv;
      }
      __syncthreads();
    }
  }
#pragma unroll
  for (int off = 1; off < 16; off <<= 1) {
#pragma unroll
    for (int i = 0; i < 4; i++) {
      s[i] += __shfl_xor(s[i], off);
      u[i] += __shfl_xor(u[i], off);
    }
  }
  if (m16 == 0) {
#pragma unroll
    for (int i = 0; i < 4; i++) {
      sWv[wave][quad * 4 + i] = s[i];
      uWv[wave][quad * 4 + i] = u[i];
    }
  }
  __syncthreads();
  if (tid < 16) {
    float S = sWv[0][tid] + sWv[1][tid] + sWv[2][tid] + sWv[3][tid];
    float U = uWv[0][tid] + uWv[1][tid] + uWv[2][tid] + uWv[3][tid];
    float er = __logf(S) - U / S;
    er += __shfl_xor(er, 1);
    er += __shfl_xor(er, 2);
    er += __shfl_xor(er, 4);
    er += __shfl_xor(er, 8);
    if (tid == 0) atomicAdd(&ent[bh], er);
  }
}

// K5: gate MLP + per-row top-k + masked softmax (no max; shift-invariant)
// + MFMA PV -> oh. XCD remap: a%8 == rowtile%8 == writer k_ent block %8.
template <bool CACHED>
__global__ __launch_bounds__(256, 7) void k_attn_t(
    const _Float16* __restrict__ q2, const _Float16* __restrict__ k2,
    const _Float16* __restrict__ vt, const _Float16* __restrict__ lgH,
    const float* __restrict__ ent, const float* __restrict__ Wg1,
    const float* __restrict__ bg1, const float* __restrict__ Wg2,
    const float* __restrict__ bg2, float* __restrict__ oh) {
  __shared__ __align__(16) _Float16 pbuf[4][2320];
  __shared__ float sS[4];
  __shared__ __align__(16) float redSh[4][64];

  // XCD-affinity decode: a%8 == rowtile%8 == (bh*144+rowtile)%8 (writer).
  int a = blockIdx.x;
  int v8 = a & 7;
  int idx = a >> 3;
  int q = idx & 3;
  int pi = idx >> 2;              // 0..143
  int bh = pi / 18;
  int rowtile = v8 + (pi % 18) * 8;
  int rowblk = rowtile * 4 + q;
  int row0 = rowblk * 4;
  int tid = threadIdx.x, lane = tid & 63, wave = tid >> 6;

  // ---- gate MLP (uniform) ----
  float eAvg = ent[bh] * (1.f / 2304.f);
  float gacc = bg2[0];
#pragma unroll
  for (int i = 0; i < 16; i++) {
    float h = fmaxf(fmaf(eAvg, Wg1[i], bg1[i]), 0.f);
    gacc = fmaf(h, Wg2[i], gacc);
  }
  float ratio = 0.9f / (1.f + __expf(-gacc)) + 0.1f;
  int kp = (int)ceilf(ratio * 2304.f);
  unsigned keep = (unsigned)min(max(kp, 1), 2304);

  // ---- phase A: own row -> 36 register floats (no max needed) ----
  float v[36];
  if (CACHED) {
    const _Float16* src = lgH + ((size_t)bh * 2304 + row0 + wave) * 2304;
    const uint4* s4 = (const uint4*)src;
#pragma unroll
    for (int it = 0; it < 4; it++) {
      uint4 r = s4[lane + it * 64];
      unpack8(r, &v[it * 8]);
    }
    {
      uint2 r2 = *(const uint2*)(src + 2048 + lane * 4);
      float2 f0 = __half22float2(*(__half2*)&r2.x);
      float2 f1 = __half22float2(*(__half2*)&r2.y);
      v[32] = f0.x; v[33] = f0.y; v[34] = f1.x; v[35] = f1.y;
    }
  } else {
    int m16 = lane & 15, quad = lane >> 4;
    const half8_t* q2v =
        (const half8_t*)(q2 + ((size_t)bh * 2304 + row0 + (m16 & 3)) * 32);
    half8_t A1 = q2v[quad];
    half8_t zh = {};
    half8_t A2 = (lane < 32) ? A1 : zh;
    const half8_t* kbase = (const half8_t*)(k2 + (size_t)bh * 2304 * 32);
#pragma unroll 4
    for (int t = 0; t < 36; t++) {
      int ct = wave * 36 + t;
      int col = ct * 16 + m16;
      const half8_t* kk = kbase + (size_t)col * 4;
      half8_t b1 = kk[quad & 1];
      half8_t b2 = kk[2 + (quad & 1)];
      floatx4 acc = {};
      acc = __builtin_amdgcn_mfma_f32_16x16x32_f16(A2, b2, acc, 0, 0, 0);
      acc = __builtin_amdgcn_mfma_f32_16x16x32_f16(A1, b1, acc, 0, 0, 0);
      if (lane < 16) {
#pragma unroll
        for (int i = 0; i < 4; i++) pbuf[i][ct * 16 + lane] = (_Float16)acc[i];
      }
    }
    __syncthreads();
    const _Float16* src = pbuf[wave];
    const uint4* s4 = (const uint4*)src;
#pragma unroll
    for (int it = 0; it < 4; it++) unpack8(s4[lane + it * 64], &v[it * 8]);
    uint2 r2 = *(const uint2*)(src + 2048 + lane * 4);
    float2 f0 = __half22float2(*(__half2*)&r2.x);
    float2 f1 = __half22float2(*(__half2*)&r2.y);
    v[32] = f0.x; v[33] = f0.y; v[34] = f1.x; v[35] = f1.y;
  }

  // ---- phase B: exact k-th largest, float-domain ballot bit-search ----
  float th;
  {
    unsigned T = 0u;
    for (int bit = 15; bit >= 0; --bit) {
      unsigned cand = T | (1u << bit);
      float cf = key16_to_float(cand);
      unsigned cnt = 0u;
#pragma unroll
      for (int i = 0; i < 36; i++)
        cnt += (unsigned)__popcll(__ballot(v[i] >= cf));
      if (cnt >= keep) {
        T = cand;  // uniform
        if (cnt == keep) break;
      }
    }
    th = key16_to_float(T);
  }

  // ---- phase C1: masked exp (raw; softmax shift-invariant); p -> LDS ----
  {
    float sp = 0.f;
    uint4* prow4 = (uint4*)pbuf[wave];
#pragma unroll
    for (int it = 0; it < 4; it++) {
      float p[8];
#pragma unroll
      for (int e = 0; e < 8; e++) {
        float av = v[it * 8 + e];
        p[e] = (av >= th) ? __expf(av) : 0.f;
        sp += p[e];
      }
      uint4 o;
      __half2 h0 = __floats2half2_rn(p[0], p[1]); o.x = *(unsigned*)&h0;
      __half2 h1 = __floats2half2_rn(p[2], p[3]); o.y = *(unsigned*)&h1;
      __half2 h2 = __floats2half2_rn(p[4], p[5]); o.z = *(unsigned*)&h2;
      __half2 h3 = __floats2half2_rn(p[6], p[7]); o.w = *(unsigned*)&h3;
      prow4[lane + it * 64] = o;
    }
    {
      float p0 = (v[32] >= th) ? __expf(v[32]) : 0.f;
      float p1 = (v[33] >= th) ? __expf(v[33]) : 0.f;
      float p2 = (v[34] >= th) ? __expf(v[34]) : 0.f;
      float p3 = (v[35] >= th) ? __expf(v[35]) : 0.f;
      sp += (p0 + p1) + (p2 + p3);
      uint2 o;
      __half2 h0 = __floats2half2_rn(p0, p1); o.x = *(unsigned*)&h0;
      __half2 h1 = __floats2half2_rn(p2, p3); o.y = *(unsigned*)&h1;
      *(uint2*)(pbuf[wave] + 2048 + lane * 4) = o;
    }
#pragma unroll
    for (int off = 1; off < 64; off <<= 1) sp += __shfl_xor(sp, off);
    if (lane == 0) sS[wave] = sp;
  }
  __syncthreads();  // all rows' p visible; sS visible

  // ---- phase C2: PV via MFMA; wave = j-quarter ----
  {
    int m16 = lane & 15, quad = lane >> 4;
    const _Float16* vrow = vt + ((size_t)bh * 16 + m16) * 2304;
    const _Float16* prow = pbuf[m16 & 3];
    int jb0 = wave * 576 + quad * 8;
    floatx4 acc = {};
#pragma unroll 6
    for (int t = 0; t < 18; t++) {
      int jb = jb0 + t * 32;
      half8_t a2 = *(const half8_t*)&prow[jb];
      half8_t b2 = *(const half8_t*)&vrow[jb];
      acc = __builtin_amdgcn_mfma_f32_16x16x32_f16(a2, b2, acc, 0, 0, 0);
    }
    if (lane < 16) {  // quad 0: D rows 0-3 = our rows, col = m16 = d
      *(floatx4*)&redSh[wave][m16 * 4] = acc;
    }
  }
  __syncthreads();
  if (tid < 64) {
    int r = tid & 3, d = tid >> 2;
    float s2 = redSh[0][d * 4 + r] + redSh[1][d * 4 + r] +
               redSh[2][d * 4 + r] + redSh[3][d * 4 + r];
    oh[((size_t)(bh * 2304 + row0 + r)) * 16 + d] = s2 / sS[r];
  }
}

// K6: output projection, 4 output channels per block. grid = 2*16*9 = 288.
__global__ __launch_bounds__(256) void k_proj(const float* __restrict__ oh,
                                              const float* __restrict__ Wp,
                                              const float* __restrict__ bp,
                                              float* __restrict__ out) {
  int blk = blockIdx.x;
  int chunk = blk % 9;
  int cog = (blk / 9) % 16;
  int b = blk / (9 * 16);
  int co0 = cog * 4;
  int pos = chunk * 256 + threadIdx.x;
  float a0 = bp[co0 + 0], a1 = bp[co0 + 1], a2 = bp[co0 + 2], a3 = bp[co0 + 3];
#pragma unroll
  for (int head = 0; head < 4; head++) {
    const float4* op =
        (const float4*)(oh + ((size_t)((b * 4 + head) * 2304 + pos)) * 16);
#pragma unroll
    for (int p = 0; p < 4; p++) {
      float4 o4 = op[p];
#pragma unroll
      for (int i = 0; i < 4; i++) {
        const float* wr = Wp + (co0 + i) * 64 + head * 16 + p * 4;
        float* ai = (i == 0) ? &a0 : ((i == 1) ? &a1 : ((i == 2) ? &a2 : &a3));
        *ai = fmaf(wr[0], o4.x, *ai);
        *ai = fmaf(wr[1], o4.y, *ai);
        *ai = fmaf(wr[2], o4.z, *ai);
        *ai = fmaf(wr[3], o4.w, *ai);
      }
    }
  }
  out[(b * 64 + co0 + 0) * 2304 + pos] = a0;
  out[(b * 64 + co0 + 1) * 2304 + pos] = a1;
  out[(b * 64 + co0 + 2) * 2304 + pos] = a2;
  out[(b * 64 + co0 + 3) * 2304 + pos] = a3;
}

extern "C" void kernel_launch(void* const* d_in, const int* in_sizes, int n_in,
                              void* d_out, int out_size, void* d_ws,
                              size_t ws_size, hipStream_t stream) {
  const float* x    = (const float*)d_in[0];
  const float* Wqkv = (const float*)d_in[1];
  const float* bqkv = (const float*)d_in[2];
  const float* Wpos = (const float*)d_in[3];
  const float* bpos = (const float*)d_in[4];
  const float* Wg1  = (const float*)d_in[5];
  const float* bg1  = (const float*)d_in[6];
  const float* Wg2  = (const float*)d_in[7];
  const float* bg2  = (const float*)d_in[8];
  const float* Wpr  = (const float*)d_in[9];
  const float* bpr  = (const float*)d_in[10];
  float* out = (float*)d_out;

  // row-major f16 logit cache: 8 bh * 2304 * 2304 * 2 B = 84,934,656 B
  const size_t lgBytes = (size_t)8 * 2304 * 2304 * 2;
  const size_t baseBytes = (size_t)(884736 + 294912 + 8) * 4 +
                           (size_t)(2 * 589824 + 294912) * 2;
  bool cached = ws_size >= lgBytes + baseBytes;

  char* base = (char*)d_ws;
  _Float16* lgH = nullptr;
  if (cached) {
    lgH = (_Float16*)base;
    base += lgBytes;
  }
  float* qkv_raw = (float*)base;        // 884736 floats
  float* oh = qkv_raw + 884736;         // 294912 floats
  float* ent = oh + 294912;             // 8 floats
  _Float16* q2 = (_Float16*)(ent + 8);  // 589824 halves
  _Float16* k2 = q2 + 589824;           // 589824 halves
  _Float16* vt = k2 + 589824;           // 294912 halves (V^T f16 [bh][d][j])

  hipLaunchKernelGGL(k_qkv, dim3(2 * 48 * 9), dim3(256), 0, stream,
                     x, Wqkv, bqkv, qkv_raw, ent);
  hipLaunchKernelGGL(k_dw, dim3(432), dim3(256), 0, stream,
                     qkv_raw, Wpos, bpos, q2, k2, vt);
  if (cached) {
    hipLaunchKernelGGL((k_ent_t<true>), dim3(8 * 144), dim3(256), 0, stream,
                       q2, k2, ent, lgH);
    hipLaunchKernelGGL((k_attn_t<true>), dim3(8 * 576), dim3(256), 0, stream,
                       q2, k2, vt, lgH, ent, Wg1, bg1, Wg2, bg2, oh);
  } else {
    hipLaunchKernelGGL((k_ent_t<false>), dim3(8 * 144), dim3(256), 0, stream,
                       q2, k2, ent, lgH);
    hipLaunchKernelGGL((k_attn_t<false>), dim3(8 * 576), dim3(256), 0, stream,
                       q2, k2, vt, lgH, ent, Wg1, bg1, Wg2, bg2, oh);
  }
  hipLaunchKernelGGL(k_proj, dim3(2 * 16 * 9), dim3(256), 0, stream,
                     oh, Wpr, bpr, out);
}